// Round 1
// baseline (1046.102 us; speedup 1.0000x reference)
//
#include <hip/hip_runtime.h>
#include <hip/hip_fp16.h>
#include <cstdint>
#include <cstddef>

#define RR     128
#define VV     (RR * RR * RR)        // 2,097,152 voxels
#define NCH    28
#define CPAD   32                    // padded channels -> 64 B per voxel (fp16)
#define CELL   8                     // cell edge in voxels
#define NCD    16                    // cells per dim (128/8)
#define NCELLS 4096                  // 16^3
#define REG    9                     // region edge = CELL+1
#define RV     (REG * REG * REG)     // 729 voxels per region

__device__ __forceinline__ unsigned short f2h(float f) {
    __half h = __float2half(f);
    return *reinterpret_cast<unsigned short*>(&h);
}
__device__ __forceinline__ float2 up2(unsigned int u) {
    __half2 h = *reinterpret_cast<__half2*>(&u);
    return __half22float2(h);
}

// Shared coordinate transform: must be bit-identical everywhere it is used.
__device__ __forceinline__ void point_coords(float x, float y, float z,
                                             float& px, float& py, float& pz,
                                             int& ix, int& iy, int& iz) {
    const float S = 63.5f / 1.5f;    // ((g/1.5)+1)*0.5*127
    px = fmaf(x, S, 63.5f);
    py = fmaf(y, S, 63.5f);
    pz = fmaf(z, S, 63.5f);
    ix = min(max((int)floorf(px), 0), RR - 2);
    iy = min(max((int)floorf(py), 0), RR - 2);
    iz = min(max((int)floorf(pz), 0), RR - 2);
}

// ---- Pass 1: per-cell histogram ----
__global__ __launch_bounds__(256) void hist_kernel(
    const float* __restrict__ xyz, unsigned int* __restrict__ cnt, int N)
{
    int n = blockIdx.x * 256 + threadIdx.x;
    if (n >= N) return;
    const float* xp = xyz + (size_t)n * 3;
    float px, py, pz; int ix, iy, iz;
    point_coords(xp[0], xp[1], xp[2], px, py, pz, ix, iy, iz);
    int cell = ((iz >> 3) * NCD + (iy >> 3)) * NCD + (ix >> 3);
    atomicAdd(&cnt[cell], 1u);
}

// ---- Pass 2: exclusive scan of 4096 counts (single block) ----
__global__ __launch_bounds__(256) void scan_kernel(
    const unsigned int* __restrict__ cnt,
    unsigned int* __restrict__ off,
    unsigned int* __restrict__ cur)
{
    __shared__ unsigned int part[256];
    int t = threadIdx.x;
    unsigned int local[16];
    unsigned int s = 0;
#pragma unroll
    for (int i = 0; i < 16; ++i) { local[i] = cnt[t * 16 + i]; s += local[i]; }
    part[t] = s;
    __syncthreads();
    for (int d = 1; d < 256; d <<= 1) {
        unsigned int v = (t >= d) ? part[t - d] : 0u;
        __syncthreads();
        part[t] += v;
        __syncthreads();
    }
    unsigned int base = (t == 0) ? 0u : part[t - 1];
#pragma unroll
    for (int i = 0; i < 16; ++i) {
        off[t * 16 + i] = base;
        cur[t * 16 + i] = base;
        base += local[i];
    }
    if (t == 255) off[NCELLS] = part[255];
}

// ---- Pass 3: scatter points into cell-sorted order (px,py,pz,idx) ----
__global__ __launch_bounds__(256) void scatter_kernel(
    const float* __restrict__ xyz, unsigned int* __restrict__ cur,
    float4* __restrict__ sorted, int N)
{
    int n = blockIdx.x * 256 + threadIdx.x;
    if (n >= N) return;
    const float* xp = xyz + (size_t)n * 3;
    float px, py, pz; int ix, iy, iz;
    point_coords(xp[0], xp[1], xp[2], px, py, pz, ix, iy, iz);
    int cell = ((iz >> 3) * NCD + (iy >> 3)) * NCD + (ix >> 3);
    unsigned int slot = atomicAdd(&cur[cell], 1u);
    sorted[slot] = make_float4(px, py, pz, __int_as_float(n));
}

// ---- Pass 4: per-cell fused presum + trilinear gather from LDS ----
// One block per cell. Region (9^3 voxels) of base+detail summed to fp16 in LDS,
// then all of the cell's points are interpolated from LDS (4 lanes/point).
__global__ __launch_bounds__(512) void cell_gather(
    const float* __restrict__ bden, const float* __restrict__ bsh,
    const float* __restrict__ dden, const float* __restrict__ dsh,
    const float4* __restrict__ sorted, const unsigned int* __restrict__ off,
    float* __restrict__ out)
{
    __shared__ unsigned short vlds[RV * CPAD];   // 46,656 B -> 3 blocks/CU

    // XCD swizzle: consecutive cells (x-neighbors, shared cache lines) on same XCD.
    int bid = blockIdx.x;
    int cid = (bid & 7) * (NCELLS / 8) + (bid >> 3);   // 4096 % 8 == 0, bijective
    int cx = cid & 15, cy = (cid >> 4) & 15, cz = cid >> 8;
    int x0 = cx << 3, y0 = cy << 3, z0 = cz << 3;
    int xlast = (cx == 15) ? 7 : 8;   // clamp 9th x for edge cells (never read)

    // --- region load: task = (c, rz, ry), 9 voxels along x each ---
    for (int task = threadIdx.x; task < 81 * CPAD; task += 512) {
        int c = task / 81;
        int r = task - c * 81;
        int rz = r / 9, ry = r - rz * 9;
        int v0 = (rz * 9 + ry) * 9;
        if (c < NCH) {
            int zg = min(z0 + rz, RR - 1);
            int yg = min(y0 + ry, RR - 1);
            size_t row = ((size_t)(zg * RR + yg)) * RR + x0;
            const float* bp; const float* dp;
            if (c == 0) { bp = bden + row; dp = dden + row; }
            else { size_t o = (size_t)(c - 1) * VV + row; bp = bsh + o; dp = dsh + o; }
            float s[9];
#pragma unroll
            for (int xx = 0; xx < 8; ++xx) s[xx] = bp[xx] + dp[xx];
            s[8] = bp[xlast] + dp[xlast];
#pragma unroll
            for (int xx = 0; xx < 9; ++xx)
                vlds[(v0 + xx) * CPAD + c] = f2h(s[xx]);
        } else {
#pragma unroll
            for (int xx = 0; xx < 9; ++xx)
                vlds[(v0 + xx) * CPAD + c] = 0;
        }
    }
    __syncthreads();

    // --- point loop: 4 lanes per point, 8 channels per lane ---
    int start = (int)off[cid], end = (int)off[cid + 1];
    int g = threadIdx.x >> 2, t = threadIdx.x & 3;

    for (int p = start + g; p < end; p += 128) {
        float4 pt = sorted[p];
        float px = pt.x, py = pt.y, pz = pt.z;
        int idx = __float_as_int(pt.w);

        float fx0 = floorf(px), fy0 = floorf(py), fz0 = floorf(pz);
        float fx = px - fx0, fy = py - fy0, fz = pz - fz0;
        int lx = min(max((int)fx0, 0), RR - 2) - x0;
        int ly = min(max((int)fy0, 0), RR - 2) - y0;
        int lz = min(max((int)fz0, 0), RR - 2) - z0;

        float wx[2] = {1.0f - fx, fx};
        float wy[2] = {1.0f - fy, fy};
        float wz[2] = {1.0f - fz, fz};

        float acc[8];
#pragma unroll
        for (int k = 0; k < 8; ++k) acc[k] = 0.0f;

#pragma unroll
        for (int dz = 0; dz < 2; ++dz)
#pragma unroll
        for (int dy = 0; dy < 2; ++dy)
#pragma unroll
        for (int dx = 0; dx < 2; ++dx) {
            int v = ((lz + dz) * 9 + (ly + dy)) * 9 + (lx + dx);
            float w = wz[dz] * wy[dy] * wx[dx];
            const uint4 q = *(const uint4*)(vlds + v * CPAD + t * 8);
            float2 p0 = up2(q.x), p1 = up2(q.y), p2 = up2(q.z), p3 = up2(q.w);
            acc[0] = fmaf(w, p0.x, acc[0]);
            acc[1] = fmaf(w, p0.y, acc[1]);
            acc[2] = fmaf(w, p1.x, acc[2]);
            acc[3] = fmaf(w, p1.y, acc[3]);
            acc[4] = fmaf(w, p2.x, acc[4]);
            acc[5] = fmaf(w, p2.y, acc[5]);
            acc[6] = fmaf(w, p3.x, acc[6]);
            acc[7] = fmaf(w, p3.y, acc[7]);
        }

        float* op = out + (size_t)idx * NCH + t * 8;
        if (t < 3) {
            *(float4*)op       = make_float4(acc[0], acc[1], acc[2], acc[3]);
            *(float4*)(op + 4) = make_float4(acc[4], acc[5], acc[6], acc[7]);
        } else {
            *(float4*)op = make_float4(acc[0], acc[1], acc[2], acc[3]); // ch 24..27
        }
    }
}

// ---- Fallback: direct dual-grid gather (used only if ws is too small) ----
__global__ __launch_bounds__(256) void gather_fallback(
    const float* __restrict__ xyz,
    const float* __restrict__ bden, const float* __restrict__ bsh,
    const float* __restrict__ dden, const float* __restrict__ dsh,
    float* __restrict__ out, int N)
{
    int n = blockIdx.x * 256 + threadIdx.x;
    if (n >= N) return;
    const float* xp = xyz + (size_t)n * 3;
    float px, py, pz; int ix, iy, iz;
    point_coords(xp[0], xp[1], xp[2], px, py, pz, ix, iy, iz);
    float fx = px - floorf(px), fy = py - floorf(py), fz = pz - floorf(pz);
    float wx[2] = {1.0f - fx, fx}, wy[2] = {1.0f - fy, fy}, wz[2] = {1.0f - fz, fz};

    int idx[8]; float w[8];
#pragma unroll
    for (int k = 0; k < 8; ++k) {
        int dz = (k >> 2) & 1, dy = (k >> 1) & 1, dx = k & 1;
        idx[k] = ((iz + dz) * RR + (iy + dy)) * RR + (ix + dx);
        w[k] = wz[dz] * wy[dy] * wx[dx];
    }
#pragma unroll
    for (int c = 0; c < NCH; ++c) {
        const float* bp = (c == 0) ? bden : (bsh + (size_t)(c - 1) * VV);
        const float* dp = (c == 0) ? dden : (dsh + (size_t)(c - 1) * VV);
        float a = 0.0f;
#pragma unroll
        for (int k = 0; k < 8; ++k)
            a = fmaf(w[k], bp[idx[k]] + dp[idx[k]], a);
        out[(size_t)n * NCH + c] = a;
    }
}

extern "C" void kernel_launch(void* const* d_in, const int* in_sizes, int n_in,
                              void* d_out, int out_size, void* d_ws, size_t ws_size,
                              hipStream_t stream) {
    const float* xyz  = (const float*)d_in[0];
    const float* bden = (const float*)d_in[1];
    const float* bsh  = (const float*)d_in[2];
    const float* dden = (const float*)d_in[3];
    const float* dsh  = (const float*)d_in[4];
    float* out = (float*)d_out;
    int N = in_sizes[0] / 3;

    size_t sortBytes = (size_t)N * sizeof(float4);
    size_t need = sortBytes + (size_t)(NCELLS + (NCELLS + 1) + NCELLS) * 4;

    if (ws_size >= need) {
        char* w = (char*)d_ws;
        float4* sorted    = (float4*)w;
        unsigned int* cnt = (unsigned int*)(w + sortBytes);
        unsigned int* off = cnt + NCELLS;
        unsigned int* cur = off + NCELLS + 1;

        hipMemsetAsync(cnt, 0, NCELLS * sizeof(unsigned int), stream);
        hist_kernel<<<(N + 255) / 256, 256, 0, stream>>>(xyz, cnt, N);
        scan_kernel<<<1, 256, 0, stream>>>(cnt, off, cur);
        scatter_kernel<<<(N + 255) / 256, 256, 0, stream>>>(xyz, cur, sorted, N);
        cell_gather<<<NCELLS, 512, 0, stream>>>(bden, bsh, dden, dsh, sorted, off, out);
    } else {
        gather_fallback<<<(N + 255) / 256, 256, 0, stream>>>(
            xyz, bden, bsh, dden, dsh, out, N);
    }
}

// Round 2
// 956.478 us; speedup vs baseline: 1.0937x; 1.0937x over previous
//
#include <hip/hip_runtime.h>
#include <hip/hip_fp16.h>
#include <cstdint>
#include <cstddef>

#define RR     128
#define VV     (RR * RR * RR)        // 2,097,152 voxels
#define NCH    28
#define CPAD   32                    // padded channels -> 64 B per voxel (fp16)
#define NCD    16                    // cells per dim (128/8)
#define NCELLS 4096                  // 16^3
#define REG    9                     // region edge = CELL+1
#define RV     (REG * REG * REG)     // 729 voxels per region

__device__ __forceinline__ unsigned short f2h(float f) {
    __half h = __float2half(f);
    return *reinterpret_cast<unsigned short*>(&h);
}
__device__ __forceinline__ float2 up2(unsigned int u) {
    __half2 h = *reinterpret_cast<__half2*>(&u);
    return __half22float2(h);
}

// Shared coordinate transform: must be bit-identical everywhere it is used.
__device__ __forceinline__ void point_coords(float x, float y, float z,
                                             float& px, float& py, float& pz,
                                             int& ix, int& iy, int& iz) {
    const float S = 63.5f / 1.5f;    // ((g/1.5)+1)*0.5*127
    px = fmaf(x, S, 63.5f);
    py = fmaf(y, S, 63.5f);
    pz = fmaf(z, S, 63.5f);
    ix = min(max((int)floorf(px), 0), RR - 2);
    iy = min(max((int)floorf(py), 0), RR - 2);
    iz = min(max((int)floorf(pz), 0), RR - 2);
}

// ---- presum: vol = base + detail (fp32 in), voxel-major fp16, 32-ch padded ----
// Coalesced streaming: 56 dword input streams, 64 B contiguous write per thread.
__global__ __launch_bounds__(256) void presum_kernel(
    const float* __restrict__ bden, const float* __restrict__ bsh,
    const float* __restrict__ dden, const float* __restrict__ dsh,
    unsigned short* __restrict__ ws)
{
    int tid = blockIdx.x * 256 + threadIdx.x;
    if (tid >= VV) return;

    unsigned short s[CPAD];
    s[0] = f2h(bden[tid] + dden[tid]);
#pragma unroll
    for (int c = 1; c < NCH; ++c) {
        size_t off = (size_t)(c - 1) * VV + tid;
        s[c] = f2h(bsh[off] + dsh[off]);
    }
#pragma unroll
    for (int c = NCH; c < CPAD; ++c) s[c] = 0;

    uint4* w = (uint4*)(ws + (size_t)tid * CPAD);
#pragma unroll
    for (int q = 0; q < 4; ++q) {
        uint4 v;
        v.x = (unsigned int)s[q*8+0] | ((unsigned int)s[q*8+1] << 16);
        v.y = (unsigned int)s[q*8+2] | ((unsigned int)s[q*8+3] << 16);
        v.z = (unsigned int)s[q*8+4] | ((unsigned int)s[q*8+5] << 16);
        v.w = (unsigned int)s[q*8+6] | ((unsigned int)s[q*8+7] << 16);
        w[q] = v;
    }
}

// ---- Pass 1: per-cell histogram ----
__global__ __launch_bounds__(256) void hist_kernel(
    const float* __restrict__ xyz, unsigned int* __restrict__ cnt, int N)
{
    int n = blockIdx.x * 256 + threadIdx.x;
    if (n >= N) return;
    const float* xp = xyz + (size_t)n * 3;
    float px, py, pz; int ix, iy, iz;
    point_coords(xp[0], xp[1], xp[2], px, py, pz, ix, iy, iz);
    int cell = ((iz >> 3) * NCD + (iy >> 3)) * NCD + (ix >> 3);
    atomicAdd(&cnt[cell], 1u);
}

// ---- Pass 2: exclusive scan of 4096 counts (single block) ----
__global__ __launch_bounds__(256) void scan_kernel(
    const unsigned int* __restrict__ cnt,
    unsigned int* __restrict__ off,
    unsigned int* __restrict__ cur)
{
    __shared__ unsigned int part[256];
    int t = threadIdx.x;
    unsigned int local[16];
    unsigned int s = 0;
#pragma unroll
    for (int i = 0; i < 16; ++i) { local[i] = cnt[t * 16 + i]; s += local[i]; }
    part[t] = s;
    __syncthreads();
    for (int d = 1; d < 256; d <<= 1) {
        unsigned int v = (t >= d) ? part[t - d] : 0u;
        __syncthreads();
        part[t] += v;
        __syncthreads();
    }
    unsigned int base = (t == 0) ? 0u : part[t - 1];
#pragma unroll
    for (int i = 0; i < 16; ++i) {
        off[t * 16 + i] = base;
        cur[t * 16 + i] = base;
        base += local[i];
    }
    if (t == 255) off[NCELLS] = part[255];
}

// ---- Pass 3: scatter points into cell-sorted order (px,py,pz,idx) ----
__global__ __launch_bounds__(256) void scatter_kernel(
    const float* __restrict__ xyz, unsigned int* __restrict__ cur,
    float4* __restrict__ sorted, int N)
{
    int n = blockIdx.x * 256 + threadIdx.x;
    if (n >= N) return;
    const float* xp = xyz + (size_t)n * 3;
    float px, py, pz; int ix, iy, iz;
    point_coords(xp[0], xp[1], xp[2], px, py, pz, ix, iy, iz);
    int cell = ((iz >> 3) * NCD + (iy >> 3)) * NCD + (ix >> 3);
    unsigned int slot = atomicAdd(&cur[cell], 1u);
    sorted[slot] = make_float4(px, py, pz, __int_as_float(n));
}

// ---- Pass 4: per-cell gather. Region copied (coalesced) from the fp16
//      presummed volume into LDS, XOR-swizzled 16B slots; then trilinear
//      interpolation from LDS, 4 lanes per point (8 channels each). ----
__global__ __launch_bounds__(512) void cell_gather(
    const unsigned short* __restrict__ vol,     // presummed fp16 volume
    const float4* __restrict__ sorted, const unsigned int* __restrict__ off,
    float* __restrict__ out)
{
    __shared__ uint4 lds16[RV * 4];   // 46,656 B -> 3 blocks/CU

    // XCD swizzle: consecutive cells (x-neighbors, shared cache lines) on same XCD.
    int bid = blockIdx.x;
    int cid = (bid & 7) * (NCELLS / 8) + (bid >> 3);   // 4096 % 8 == 0, bijective
    int cx = cid & 15, cy = (cid >> 4) & 15, cz = cid >> 8;
    int x0 = cx << 3, y0 = cy << 3, z0 = cz << 3;

    // --- region copy: 2916 x 16B, consecutive lanes -> consecutive 16B.
    //     LDS write slot XOR-swizzled by (v&3) so gather reads are ~2-way. ---
    for (int i = threadIdx.x; i < RV * 4; i += 512) {
        int v = i >> 2, j = i & 3;
        int rz = v / 81, rem = v - rz * 81;
        int ry = rem / 9, rx = rem - ry * 9;
        int zg = min(z0 + rz, RR - 1);
        int yg = min(y0 + ry, RR - 1);
        int xg = min(x0 + rx, RR - 1);
        const uint4* src = (const uint4*)(vol + (size_t)((zg * RR + yg) * RR + xg) * CPAD);
        lds16[v * 4 + (j ^ (v & 3))] = src[j];
    }
    __syncthreads();

    // --- point loop: 4 lanes per point, 8 channels per lane ---
    int start = (int)off[cid], end = (int)off[cid + 1];
    int g = threadIdx.x >> 2, t = threadIdx.x & 3;

    for (int p = start + g; p < end; p += 128) {
        float4 pt = sorted[p];
        float px = pt.x, py = pt.y, pz = pt.z;
        int idx = __float_as_int(pt.w);

        float fx0 = floorf(px), fy0 = floorf(py), fz0 = floorf(pz);
        float fx = px - fx0, fy = py - fy0, fz = pz - fz0;
        int lx = min(max((int)fx0, 0), RR - 2) - x0;
        int ly = min(max((int)fy0, 0), RR - 2) - y0;
        int lz = min(max((int)fz0, 0), RR - 2) - z0;

        float wx[2] = {1.0f - fx, fx};
        float wy[2] = {1.0f - fy, fy};
        float wz[2] = {1.0f - fz, fz};

        float acc[8];
#pragma unroll
        for (int k = 0; k < 8; ++k) acc[k] = 0.0f;

#pragma unroll
        for (int dz = 0; dz < 2; ++dz)
#pragma unroll
        for (int dy = 0; dy < 2; ++dy)
#pragma unroll
        for (int dx = 0; dx < 2; ++dx) {
            int v = ((lz + dz) * 9 + (ly + dy)) * 9 + (lx + dx);
            float w = wz[dz] * wy[dy] * wx[dx];
            const uint4 q = lds16[v * 4 + (t ^ (v & 3))];
            float2 p0 = up2(q.x), p1 = up2(q.y), p2 = up2(q.z), p3 = up2(q.w);
            acc[0] = fmaf(w, p0.x, acc[0]);
            acc[1] = fmaf(w, p0.y, acc[1]);
            acc[2] = fmaf(w, p1.x, acc[2]);
            acc[3] = fmaf(w, p1.y, acc[3]);
            acc[4] = fmaf(w, p2.x, acc[4]);
            acc[5] = fmaf(w, p2.y, acc[5]);
            acc[6] = fmaf(w, p3.x, acc[6]);
            acc[7] = fmaf(w, p3.y, acc[7]);
        }

        float* op = out + (size_t)idx * NCH + t * 8;
        if (t < 3) {
            *(float4*)op       = make_float4(acc[0], acc[1], acc[2], acc[3]);
            *(float4*)(op + 4) = make_float4(acc[4], acc[5], acc[6], acc[7]);
        } else {
            *(float4*)op = make_float4(acc[0], acc[1], acc[2], acc[3]); // ch 24..27
        }
    }
}

// ---- Mid fallback: direct gather from presummed volume (round-0 kernel) ----
__global__ __launch_bounds__(256) void gather_kernel(
    const float* __restrict__ xyz,
    const unsigned short* __restrict__ vol,
    float* __restrict__ out, int N)
{
    int tid = blockIdx.x * 256 + threadIdx.x;
    int n = tid >> 2;
    int t = tid & 3;
    if (n >= N) return;

    const float* xp = xyz + (size_t)n * 3;
    float px, py, pz; int ix, iy, iz;
    point_coords(xp[0], xp[1], xp[2], px, py, pz, ix, iy, iz);
    float fx = px - floorf(px), fy = py - floorf(py), fz = pz - floorf(pz);
    float wx[2] = {1.0f - fx, fx}, wy[2] = {1.0f - fy, fy}, wz[2] = {1.0f - fz, fz};

    int ibase = (iz * RR + iy) * RR + ix;
    const char* basep = (const char*)vol + (size_t)t * 16;

    float acc[8];
#pragma unroll
    for (int k = 0; k < 8; ++k) acc[k] = 0.0f;

#pragma unroll
    for (int dz = 0; dz < 2; ++dz)
#pragma unroll
    for (int dy = 0; dy < 2; ++dy)
#pragma unroll
    for (int dx = 0; dx < 2; ++dx) {
        int vidx = ibase + dz * (RR * RR) + dy * RR + dx;
        float w = wz[dz] * wy[dy] * wx[dx];
        const uint4 q = *(const uint4*)(basep + (size_t)vidx * (CPAD * 2));
        float2 p0 = up2(q.x), p1 = up2(q.y), p2 = up2(q.z), p3 = up2(q.w);
        acc[0] = fmaf(w, p0.x, acc[0]);
        acc[1] = fmaf(w, p0.y, acc[1]);
        acc[2] = fmaf(w, p1.x, acc[2]);
        acc[3] = fmaf(w, p1.y, acc[3]);
        acc[4] = fmaf(w, p2.x, acc[4]);
        acc[5] = fmaf(w, p2.y, acc[5]);
        acc[6] = fmaf(w, p3.x, acc[6]);
        acc[7] = fmaf(w, p3.y, acc[7]);
    }

    float* op = out + (size_t)n * NCH + t * 8;
    if (t < 3) {
        *(float4*)op       = make_float4(acc[0], acc[1], acc[2], acc[3]);
        *(float4*)(op + 4) = make_float4(acc[4], acc[5], acc[6], acc[7]);
    } else {
        *(float4*)op = make_float4(acc[0], acc[1], acc[2], acc[3]);
    }
}

// ---- Last-resort fallback: direct dual-grid gather ----
__global__ __launch_bounds__(256) void gather_fallback(
    const float* __restrict__ xyz,
    const float* __restrict__ bden, const float* __restrict__ bsh,
    const float* __restrict__ dden, const float* __restrict__ dsh,
    float* __restrict__ out, int N)
{
    int n = blockIdx.x * 256 + threadIdx.x;
    if (n >= N) return;
    const float* xp = xyz + (size_t)n * 3;
    float px, py, pz; int ix, iy, iz;
    point_coords(xp[0], xp[1], xp[2], px, py, pz, ix, iy, iz);
    float fx = px - floorf(px), fy = py - floorf(py), fz = pz - floorf(pz);
    float wx[2] = {1.0f - fx, fx}, wy[2] = {1.0f - fy, fy}, wz[2] = {1.0f - fz, fz};

    int idx[8]; float w[8];
#pragma unroll
    for (int k = 0; k < 8; ++k) {
        int dz = (k >> 2) & 1, dy = (k >> 1) & 1, dx = k & 1;
        idx[k] = ((iz + dz) * RR + (iy + dy)) * RR + (ix + dx);
        w[k] = wz[dz] * wy[dy] * wx[dx];
    }
#pragma unroll
    for (int c = 0; c < NCH; ++c) {
        const float* bp = (c == 0) ? bden : (bsh + (size_t)(c - 1) * VV);
        const float* dp = (c == 0) ? dden : (dsh + (size_t)(c - 1) * VV);
        float a = 0.0f;
#pragma unroll
        for (int k = 0; k < 8; ++k)
            a = fmaf(w[k], bp[idx[k]] + dp[idx[k]], a);
        out[(size_t)n * NCH + c] = a;
    }
}

extern "C" void kernel_launch(void* const* d_in, const int* in_sizes, int n_in,
                              void* d_out, int out_size, void* d_ws, size_t ws_size,
                              hipStream_t stream) {
    const float* xyz  = (const float*)d_in[0];
    const float* bden = (const float*)d_in[1];
    const float* bsh  = (const float*)d_in[2];
    const float* dden = (const float*)d_in[3];
    const float* dsh  = (const float*)d_in[4];
    float* out = (float*)d_out;
    int N = in_sizes[0] / 3;

    size_t volBytes  = (size_t)VV * CPAD * sizeof(unsigned short);  // 134 MB
    size_t sortBytes = (size_t)N * sizeof(float4);                  // 32 MB
    size_t ctrBytes  = (size_t)(NCELLS + (NCELLS + 1) + NCELLS) * 4;
    size_t needFull  = volBytes + sortBytes + ctrBytes;

    if (ws_size >= needFull) {
        char* w = (char*)d_ws;
        unsigned short* vol = (unsigned short*)w;
        float4* sorted      = (float4*)(w + volBytes);
        unsigned int* cnt   = (unsigned int*)(w + volBytes + sortBytes);
        unsigned int* off   = cnt + NCELLS;
        unsigned int* cur   = off + NCELLS + 1;

        presum_kernel<<<(VV + 255) / 256, 256, 0, stream>>>(bden, bsh, dden, dsh, vol);
        hipMemsetAsync(cnt, 0, NCELLS * sizeof(unsigned int), stream);
        hist_kernel<<<(N + 255) / 256, 256, 0, stream>>>(xyz, cnt, N);
        scan_kernel<<<1, 256, 0, stream>>>(cnt, off, cur);
        scatter_kernel<<<(N + 255) / 256, 256, 0, stream>>>(xyz, cur, sorted, N);
        cell_gather<<<NCELLS, 512, 0, stream>>>(vol, sorted, off, out);
    } else if (ws_size >= volBytes) {
        presum_kernel<<<(VV + 255) / 256, 256, 0, stream>>>(
            bden, bsh, dden, dsh, (unsigned short*)d_ws);
        long long threads = (long long)N * 4;
        gather_kernel<<<(unsigned int)((threads + 255) / 256), 256, 0, stream>>>(
            xyz, (const unsigned short*)d_ws, out, N);
    } else {
        gather_fallback<<<(N + 255) / 256, 256, 0, stream>>>(
            xyz, bden, bsh, dden, dsh, out, N);
    }
}

// Round 3
// 799.345 us; speedup vs baseline: 1.3087x; 1.1966x over previous
//
#include <hip/hip_runtime.h>
#include <hip/hip_fp16.h>
#include <cstdint>
#include <cstddef>

#define RR     128
#define VV     (RR * RR * RR)        // 2,097,152 voxels
#define NCH    28
#define CPAD   32                    // padded channels -> 64 B per voxel (fp16)
#define NCD    16                    // cells per dim (128/8)
#define NCELLS 4096                  // 16^3
#define REG    9                     // region edge = CELL+1
#define RV     (REG * REG * REG)     // 729 voxels per region
#define CAPMAX 768                   // slots per cell (mean 488, sigma ~22)
#define CAPMIN 576                   // below this, capacity scheme too risky
#define OVFCAP 262144                // overflow list capacity (1 MB)

__device__ __forceinline__ unsigned short f2h(float f) {
    __half h = __float2half(f);
    return *reinterpret_cast<unsigned short*>(&h);
}
__device__ __forceinline__ float2 up2(unsigned int u) {
    __half2 h = *reinterpret_cast<__half2*>(&u);
    return __half22float2(h);
}

// Shared coordinate transform: must be bit-identical everywhere it is used.
__device__ __forceinline__ void point_coords(float x, float y, float z,
                                             float& px, float& py, float& pz,
                                             int& ix, int& iy, int& iz) {
    const float S = 63.5f / 1.5f;    // ((g/1.5)+1)*0.5*127
    px = fmaf(x, S, 63.5f);
    py = fmaf(y, S, 63.5f);
    pz = fmaf(z, S, 63.5f);
    ix = min(max((int)floorf(px), 0), RR - 2);
    iy = min(max((int)floorf(py), 0), RR - 2);
    iz = min(max((int)floorf(pz), 0), RR - 2);
}

__device__ __forceinline__ void presum_body(
    int tid,
    const float* __restrict__ bden, const float* __restrict__ bsh,
    const float* __restrict__ dden, const float* __restrict__ dsh,
    unsigned short* __restrict__ ws)
{
    if (tid >= VV) return;
    unsigned short s[CPAD];
    s[0] = f2h(bden[tid] + dden[tid]);
#pragma unroll
    for (int c = 1; c < NCH; ++c) {
        size_t off = (size_t)(c - 1) * VV + tid;
        s[c] = f2h(bsh[off] + dsh[off]);
    }
#pragma unroll
    for (int c = NCH; c < CPAD; ++c) s[c] = 0;

    uint4* w = (uint4*)(ws + (size_t)tid * CPAD);
#pragma unroll
    for (int q = 0; q < 4; ++q) {
        uint4 v;
        v.x = (unsigned int)s[q*8+0] | ((unsigned int)s[q*8+1] << 16);
        v.y = (unsigned int)s[q*8+2] | ((unsigned int)s[q*8+3] << 16);
        v.z = (unsigned int)s[q*8+4] | ((unsigned int)s[q*8+5] << 16);
        v.w = (unsigned int)s[q*8+6] | ((unsigned int)s[q*8+7] << 16);
        w[q] = v;
    }
}

// ---- Fused pass 1: blocks [0,presumBlocks) stream presum; the rest scatter
//      points into fixed-capacity cell buckets (overflow -> list). ----
__global__ __launch_bounds__(256) void presum_scatter(
    const float* __restrict__ bden, const float* __restrict__ bsh,
    const float* __restrict__ dden, const float* __restrict__ dsh,
    const float* __restrict__ xyz, int N, int CAP,
    unsigned short* __restrict__ vol, float4* __restrict__ sorted,
    unsigned int* __restrict__ cur, unsigned int* __restrict__ ovf,
    unsigned int* __restrict__ ovfcnt, int presumBlocks)
{
    int b = blockIdx.x;
    if (b < presumBlocks) {
        presum_body(b * 256 + threadIdx.x, bden, bsh, dden, dsh, vol);
        return;
    }
    int n = (b - presumBlocks) * 256 + threadIdx.x;
    if (n >= N) return;
    const float* xp = xyz + (size_t)n * 3;
    float px, py, pz; int ix, iy, iz;
    point_coords(xp[0], xp[1], xp[2], px, py, pz, ix, iy, iz);
    int cell = ((iz >> 3) * NCD + (iy >> 3)) * NCD + (ix >> 3);
    unsigned int slot = atomicAdd(&cur[cell], 1u);
    if (slot < (unsigned int)CAP) {
        sorted[(size_t)cell * CAP + slot] = make_float4(px, py, pz, __int_as_float(n));
    } else {
        unsigned int o = atomicAdd(ovfcnt, 1u);
        if (o < (unsigned int)OVFCAP) ovf[o] = n;
    }
}

// ---- Pass 2: per-cell gather. Region copied (coalesced) from the fp16
//      presummed volume into LDS, XOR-swizzled 16B slots; then trilinear
//      interpolation from LDS, 4 lanes per point (8 channels each). ----
__global__ __launch_bounds__(512) void cell_gather(
    const unsigned short* __restrict__ vol,
    const float4* __restrict__ sorted, const unsigned int* __restrict__ cur,
    int CAP, float* __restrict__ out)
{
    __shared__ uint4 lds16[RV * 4];   // 46,656 B -> 3 blocks/CU

    // XCD swizzle: consecutive cells (x-neighbors, shared cache lines) on same XCD.
    int bid = blockIdx.x;
    int cid = (bid & 7) * (NCELLS / 8) + (bid >> 3);   // 4096 % 8 == 0, bijective
    int cx = cid & 15, cy = (cid >> 4) & 15, cz = cid >> 8;
    int x0 = cx << 3, y0 = cy << 3, z0 = cz << 3;

    // --- region copy: 2916 x 16B, consecutive lanes -> consecutive 16B.
    //     LDS write slot XOR-swizzled by (v&3) so gather reads are ~2-way. ---
    for (int i = threadIdx.x; i < RV * 4; i += 512) {
        int v = i >> 2, j = i & 3;
        int rz = v / 81, rem = v - rz * 81;
        int ry = rem / 9, rx = rem - ry * 9;
        int zg = min(z0 + rz, RR - 1);
        int yg = min(y0 + ry, RR - 1);
        int xg = min(x0 + rx, RR - 1);
        const uint4* src = (const uint4*)(vol + (size_t)((zg * RR + yg) * RR + xg) * CPAD);
        lds16[v * 4 + (j ^ (v & 3))] = src[j];
    }
    __syncthreads();

    // --- point loop: 4 lanes per point, 8 channels per lane ---
    int cnt = (int)min(cur[cid], (unsigned int)CAP);
    const float4* sp = sorted + (size_t)cid * CAP;
    int g = threadIdx.x >> 2, t = threadIdx.x & 3;

    for (int p = g; p < cnt; p += 128) {
        float4 pt = sp[p];
        float px = pt.x, py = pt.y, pz = pt.z;
        int idx = __float_as_int(pt.w);

        float fx0 = floorf(px), fy0 = floorf(py), fz0 = floorf(pz);
        float fx = px - fx0, fy = py - fy0, fz = pz - fz0;
        int lx = min(max((int)fx0, 0), RR - 2) - x0;
        int ly = min(max((int)fy0, 0), RR - 2) - y0;
        int lz = min(max((int)fz0, 0), RR - 2) - z0;

        float wx[2] = {1.0f - fx, fx};
        float wy[2] = {1.0f - fy, fy};
        float wz[2] = {1.0f - fz, fz};

        float acc[8];
#pragma unroll
        for (int k = 0; k < 8; ++k) acc[k] = 0.0f;

#pragma unroll
        for (int dz = 0; dz < 2; ++dz)
#pragma unroll
        for (int dy = 0; dy < 2; ++dy)
#pragma unroll
        for (int dx = 0; dx < 2; ++dx) {
            int v = ((lz + dz) * 9 + (ly + dy)) * 9 + (lx + dx);
            float w = wz[dz] * wy[dy] * wx[dx];
            const uint4 q = lds16[v * 4 + (t ^ (v & 3))];
            float2 p0 = up2(q.x), p1 = up2(q.y), p2 = up2(q.z), p3 = up2(q.w);
            acc[0] = fmaf(w, p0.x, acc[0]);
            acc[1] = fmaf(w, p0.y, acc[1]);
            acc[2] = fmaf(w, p1.x, acc[2]);
            acc[3] = fmaf(w, p1.y, acc[3]);
            acc[4] = fmaf(w, p2.x, acc[4]);
            acc[5] = fmaf(w, p2.y, acc[5]);
            acc[6] = fmaf(w, p3.x, acc[6]);
            acc[7] = fmaf(w, p3.y, acc[7]);
        }

        float* op = out + (size_t)idx * NCH + t * 8;
        if (t < 3) {
            *(float4*)op       = make_float4(acc[0], acc[1], acc[2], acc[3]);
            *(float4*)(op + 4) = make_float4(acc[4], acc[5], acc[6], acc[7]);
        } else {
            *(float4*)op = make_float4(acc[0], acc[1], acc[2], acc[3]); // ch 24..27
        }
    }
}

// ---- Tail: exact handling of overflowed points (normally zero). Math order
//      mirrors cell_gather exactly (same fp16 decode, same fma order). ----
__global__ __launch_bounds__(256) void tail_gather(
    const float* __restrict__ xyz, const unsigned short* __restrict__ vol,
    const unsigned int* __restrict__ ovf, const unsigned int* __restrict__ ovfcnt,
    float* __restrict__ out)
{
    int m = (int)min(*ovfcnt, (unsigned int)OVFCAP);
    for (int i = blockIdx.x * 256 + threadIdx.x; i < m; i += gridDim.x * 256) {
        int n = (int)ovf[i];
        const float* xp = xyz + (size_t)n * 3;
        float px, py, pz; int ix, iy, iz;
        point_coords(xp[0], xp[1], xp[2], px, py, pz, ix, iy, iz);
        float fx = px - floorf(px), fy = py - floorf(py), fz = pz - floorf(pz);
        float wx[2] = {1.0f - fx, fx}, wy[2] = {1.0f - fy, fy}, wz[2] = {1.0f - fz, fz};
        int ibase = (iz * RR + iy) * RR + ix;
        for (int t = 0; t < 4; ++t) {
            float acc[8];
#pragma unroll
            for (int k = 0; k < 8; ++k) acc[k] = 0.0f;
#pragma unroll
            for (int dz = 0; dz < 2; ++dz)
#pragma unroll
            for (int dy = 0; dy < 2; ++dy)
#pragma unroll
            for (int dx = 0; dx < 2; ++dx) {
                int vidx = ibase + dz * (RR * RR) + dy * RR + dx;
                float w = wz[dz] * wy[dy] * wx[dx];
                const uint4 q = *(const uint4*)((const char*)vol + (size_t)vidx * (CPAD * 2) + t * 16);
                float2 p0 = up2(q.x), p1 = up2(q.y), p2 = up2(q.z), p3 = up2(q.w);
                acc[0] = fmaf(w, p0.x, acc[0]);
                acc[1] = fmaf(w, p0.y, acc[1]);
                acc[2] = fmaf(w, p1.x, acc[2]);
                acc[3] = fmaf(w, p1.y, acc[3]);
                acc[4] = fmaf(w, p2.x, acc[4]);
                acc[5] = fmaf(w, p2.y, acc[5]);
                acc[6] = fmaf(w, p3.x, acc[6]);
                acc[7] = fmaf(w, p3.y, acc[7]);
            }
            float* op = out + (size_t)n * NCH + t * 8;
            if (t < 3) {
                *(float4*)op       = make_float4(acc[0], acc[1], acc[2], acc[3]);
                *(float4*)(op + 4) = make_float4(acc[4], acc[5], acc[6], acc[7]);
            } else {
                *(float4*)op = make_float4(acc[0], acc[1], acc[2], acc[3]);
            }
        }
    }
}

// ---- standalone presum (fallback paths) ----
__global__ __launch_bounds__(256) void presum_kernel(
    const float* __restrict__ bden, const float* __restrict__ bsh,
    const float* __restrict__ dden, const float* __restrict__ dsh,
    unsigned short* __restrict__ ws)
{
    presum_body(blockIdx.x * 256 + threadIdx.x, bden, bsh, dden, dsh, ws);
}

// ---- Mid fallback: direct gather from presummed volume (round-0 kernel) ----
__global__ __launch_bounds__(256) void gather_kernel(
    const float* __restrict__ xyz,
    const unsigned short* __restrict__ vol,
    float* __restrict__ out, int N)
{
    int tid = blockIdx.x * 256 + threadIdx.x;
    int n = tid >> 2;
    int t = tid & 3;
    if (n >= N) return;

    const float* xp = xyz + (size_t)n * 3;
    float px, py, pz; int ix, iy, iz;
    point_coords(xp[0], xp[1], xp[2], px, py, pz, ix, iy, iz);
    float fx = px - floorf(px), fy = py - floorf(py), fz = pz - floorf(pz);
    float wx[2] = {1.0f - fx, fx}, wy[2] = {1.0f - fy, fy}, wz[2] = {1.0f - fz, fz};

    int ibase = (iz * RR + iy) * RR + ix;
    const char* basep = (const char*)vol + (size_t)t * 16;

    float acc[8];
#pragma unroll
    for (int k = 0; k < 8; ++k) acc[k] = 0.0f;

#pragma unroll
    for (int dz = 0; dz < 2; ++dz)
#pragma unroll
    for (int dy = 0; dy < 2; ++dy)
#pragma unroll
    for (int dx = 0; dx < 2; ++dx) {
        int vidx = ibase + dz * (RR * RR) + dy * RR + dx;
        float w = wz[dz] * wy[dy] * wx[dx];
        const uint4 q = *(const uint4*)(basep + (size_t)vidx * (CPAD * 2));
        float2 p0 = up2(q.x), p1 = up2(q.y), p2 = up2(q.z), p3 = up2(q.w);
        acc[0] = fmaf(w, p0.x, acc[0]);
        acc[1] = fmaf(w, p0.y, acc[1]);
        acc[2] = fmaf(w, p1.x, acc[2]);
        acc[3] = fmaf(w, p1.y, acc[3]);
        acc[4] = fmaf(w, p2.x, acc[4]);
        acc[5] = fmaf(w, p2.y, acc[5]);
        acc[6] = fmaf(w, p3.x, acc[6]);
        acc[7] = fmaf(w, p3.y, acc[7]);
    }

    float* op = out + (size_t)n * NCH + t * 8;
    if (t < 3) {
        *(float4*)op       = make_float4(acc[0], acc[1], acc[2], acc[3]);
        *(float4*)(op + 4) = make_float4(acc[4], acc[5], acc[6], acc[7]);
    } else {
        *(float4*)op = make_float4(acc[0], acc[1], acc[2], acc[3]);
    }
}

// ---- Last-resort fallback: direct dual-grid gather ----
__global__ __launch_bounds__(256) void gather_fallback(
    const float* __restrict__ xyz,
    const float* __restrict__ bden, const float* __restrict__ bsh,
    const float* __restrict__ dden, const float* __restrict__ dsh,
    float* __restrict__ out, int N)
{
    int n = blockIdx.x * 256 + threadIdx.x;
    if (n >= N) return;
    const float* xp = xyz + (size_t)n * 3;
    float px, py, pz; int ix, iy, iz;
    point_coords(xp[0], xp[1], xp[2], px, py, pz, ix, iy, iz);
    float fx = px - floorf(px), fy = py - floorf(py), fz = pz - floorf(pz);
    float wx[2] = {1.0f - fx, fx}, wy[2] = {1.0f - fy, fy}, wz[2] = {1.0f - fz, fz};

    int idx[8]; float w[8];
#pragma unroll
    for (int k = 0; k < 8; ++k) {
        int dz = (k >> 2) & 1, dy = (k >> 1) & 1, dx = k & 1;
        idx[k] = ((iz + dz) * RR + (iy + dy)) * RR + (ix + dx);
        w[k] = wz[dz] * wy[dy] * wx[dx];
    }
#pragma unroll
    for (int c = 0; c < NCH; ++c) {
        const float* bp = (c == 0) ? bden : (bsh + (size_t)(c - 1) * VV);
        const float* dp = (c == 0) ? dden : (dsh + (size_t)(c - 1) * VV);
        float a = 0.0f;
#pragma unroll
        for (int k = 0; k < 8; ++k)
            a = fmaf(w[k], bp[idx[k]] + dp[idx[k]], a);
        out[(size_t)n * NCH + c] = a;
    }
}

extern "C" void kernel_launch(void* const* d_in, const int* in_sizes, int n_in,
                              void* d_out, int out_size, void* d_ws, size_t ws_size,
                              hipStream_t stream) {
    const float* xyz  = (const float*)d_in[0];
    const float* bden = (const float*)d_in[1];
    const float* bsh  = (const float*)d_in[2];
    const float* dden = (const float*)d_in[3];
    const float* dsh  = (const float*)d_in[4];
    float* out = (float*)d_out;
    int N = in_sizes[0] / 3;

    size_t volBytes = (size_t)VV * CPAD * sizeof(unsigned short);   // 134,217,728
    size_t ovfBytes = (size_t)OVFCAP * 4;                           // 1 MB
    size_t ctrBytes = (size_t)(NCELLS + 1) * 4;                     // cur + ovfcnt

    // Adaptive per-cell capacity from available workspace.
    long long availForSorted = (long long)ws_size - (long long)(volBytes + ovfBytes + ctrBytes + 64);
    int CAP = 0;
    if (availForSorted > 0) {
        long long c = availForSorted / ((long long)NCELLS * 16);
        CAP = (int)(c > CAPMAX ? CAPMAX : c);
    }

    if (CAP >= CAPMIN) {
        // layout: sorted | vol | ovf | cur | ovfcnt
        char* w = (char*)d_ws;
        float4* sorted      = (float4*)w;
        size_t sortedBytes  = (size_t)NCELLS * CAP * 16;
        unsigned short* vol = (unsigned short*)(w + sortedBytes);
        unsigned int* ovf   = (unsigned int*)(w + sortedBytes + volBytes);
        unsigned int* cur   = (unsigned int*)(w + sortedBytes + volBytes + ovfBytes);
        unsigned int* ovfcnt = cur + NCELLS;

        hipMemsetAsync(cur, 0, (NCELLS + 1) * sizeof(unsigned int), stream);
        int presumBlocks  = (VV + 255) / 256;
        int scatterBlocks = (N + 255) / 256;
        presum_scatter<<<presumBlocks + scatterBlocks, 256, 0, stream>>>(
            bden, bsh, dden, dsh, xyz, N, CAP,
            vol, sorted, cur, ovf, ovfcnt, presumBlocks);
        cell_gather<<<NCELLS, 512, 0, stream>>>(vol, sorted, cur, CAP, out);
        tail_gather<<<32, 256, 0, stream>>>(xyz, vol, ovf, ovfcnt, out);
    } else if (ws_size >= volBytes) {
        presum_kernel<<<(VV + 255) / 256, 256, 0, stream>>>(
            bden, bsh, dden, dsh, (unsigned short*)d_ws);
        long long threads = (long long)N * 4;
        gather_kernel<<<(unsigned int)((threads + 255) / 256), 256, 0, stream>>>(
            xyz, (const unsigned short*)d_ws, out, N);
    } else {
        gather_fallback<<<(N + 255) / 256, 256, 0, stream>>>(
            xyz, bden, bsh, dden, dsh, out, N);
    }
}

// Round 4
// 748.960 us; speedup vs baseline: 1.3967x; 1.0673x over previous
//
#include <hip/hip_runtime.h>
#include <hip/hip_fp16.h>
#include <cstdint>
#include <cstddef>
#include <cmath>

#define RR     128
#define VV     (RR * RR * RR)        // 2,097,152 voxels
#define NCH    28
#define CPAD   32                    // padded channels -> 64 B per voxel (fp16)
#define NCD    16                    // cells per dim (128/8)
#define NCELLS 4096                  // 16^3
#define NSUB   8                     // sub-buckets per cell (≈ per-XCD)
#define REG    9                     // region edge = CELL+1
#define RV     (REG * REG * REG)     // 729 voxels per region
#define OVFCAP (1 << 20)             // overflow list capacity (4 MB)
#define TAILB  32                    // tail blocks appended to cell_gather grid

__device__ __forceinline__ unsigned short f2h(float f) {
    __half h = __float2half(f);
    return *reinterpret_cast<unsigned short*>(&h);
}
__device__ __forceinline__ float2 up2(unsigned int u) {
    __half2 h = *reinterpret_cast<__half2*>(&u);
    return __half22float2(h);
}

// Volume chunk address (uint4 units): chunk q (16 B) of voxel V.
// Layout: 64-voxel groups; within a group, q-planes of 64 x 16 B.
// -> presum wave (64 lanes = 1 group) stores 4 x 1 KB fully coalesced.
__device__ __forceinline__ size_t chunk_at(int V, int q) {
    return ((size_t)(V >> 6)) * 256 + (q << 6) + (V & 63);
}

// Shared coordinate transform: must be bit-identical everywhere it is used.
__device__ __forceinline__ void point_coords(float x, float y, float z,
                                             float& px, float& py, float& pz,
                                             int& ix, int& iy, int& iz) {
    const float S = 63.5f / 1.5f;    // ((g/1.5)+1)*0.5*127
    px = fmaf(x, S, 63.5f);
    py = fmaf(y, S, 63.5f);
    pz = fmaf(z, S, 63.5f);
    ix = min(max((int)floorf(px), 0), RR - 2);
    iy = min(max((int)floorf(py), 0), RR - 2);
    iz = min(max((int)floorf(pz), 0), RR - 2);
}

// Trilinear 8-corner accumulate for one 16 B chunk stream (8 channels).
__device__ __forceinline__ void corner_accum(
    const uint4 q, float w, float* acc)
{
    float2 p0 = up2(q.x), p1 = up2(q.y), p2 = up2(q.z), p3 = up2(q.w);
    acc[0] = fmaf(w, p0.x, acc[0]);
    acc[1] = fmaf(w, p0.y, acc[1]);
    acc[2] = fmaf(w, p1.x, acc[2]);
    acc[3] = fmaf(w, p1.y, acc[3]);
    acc[4] = fmaf(w, p2.x, acc[4]);
    acc[5] = fmaf(w, p2.y, acc[5]);
    acc[6] = fmaf(w, p3.x, acc[6]);
    acc[7] = fmaf(w, p3.y, acc[7]);
}

// presum one voxel: load all channels first (high MLP), pack fp16, store
// 4 x 1 KB coalesced per wave via the group layout.
__device__ __forceinline__ void presum_body(
    int tid,
    const float* __restrict__ bden, const float* __restrict__ bsh,
    const float* __restrict__ dden, const float* __restrict__ dsh,
    unsigned short* __restrict__ vol)
{
    if (tid >= VV) return;
    float vb[27], vd[27];
    float v0 = bden[tid] + dden[tid];
#pragma unroll
    for (int c = 0; c < 27; ++c) vb[c] = bsh[(size_t)c * VV + tid];
#pragma unroll
    for (int c = 0; c < 27; ++c) vd[c] = dsh[(size_t)c * VV + tid];

    unsigned short s[CPAD];
    s[0] = f2h(v0);
#pragma unroll
    for (int c = 0; c < 27; ++c) s[c + 1] = f2h(vb[c] + vd[c]);
#pragma unroll
    for (int c = NCH; c < CPAD; ++c) s[c] = 0;

    uint4* volq = (uint4*)vol;
    int grp = tid >> 6, lane = tid & 63;
#pragma unroll
    for (int q = 0; q < 4; ++q) {
        uint4 v;
        v.x = (unsigned int)s[q*8+0] | ((unsigned int)s[q*8+1] << 16);
        v.y = (unsigned int)s[q*8+2] | ((unsigned int)s[q*8+3] << 16);
        v.z = (unsigned int)s[q*8+4] | ((unsigned int)s[q*8+5] << 16);
        v.w = (unsigned int)s[q*8+6] | ((unsigned int)s[q*8+7] << 16);
        volq[(size_t)grp * 256 + (q << 6) + lane] = v;
    }
}

// ---- Fused pass 1: blocks [0,presumBlocks) stream presum; the rest scatter
//      points into per-XCD sub-buckets (overflow -> exact list). ----
__global__ __launch_bounds__(256, 4) void presum_scatter(
    const float* __restrict__ bden, const float* __restrict__ bsh,
    const float* __restrict__ dden, const float* __restrict__ dsh,
    const float* __restrict__ xyz, int N, int CAPS,
    unsigned short* __restrict__ vol, float4* __restrict__ sorted,
    unsigned int* __restrict__ cur, unsigned int* __restrict__ ovf,
    unsigned int* __restrict__ ovfcnt, int presumBlocks)
{
    int b = blockIdx.x;
    if (b < presumBlocks) {
        presum_body(b * 256 + threadIdx.x, bden, bsh, dden, dsh, vol);
        return;
    }
    int n = (b - presumBlocks) * 256 + threadIdx.x;
    if (n >= N) return;
    const float* xp = xyz + (size_t)n * 3;
    float px, py, pz; int ix, iy, iz;
    point_coords(xp[0], xp[1], xp[2], px, py, pz, ix, iy, iz);
    int cell = ((iz >> 3) * NCD + (iy >> 3)) * NCD + (ix >> 3);
    int sub = b & 7;   // round-robin dispatch -> sub ≈ XCD id (perf heuristic only)
    unsigned int slot = atomicAdd(&cur[sub * NCELLS + cell], 1u);
    if (slot < (unsigned int)CAPS) {
        sorted[((size_t)sub * NCELLS + cell) * CAPS + slot] =
            make_float4(px, py, pz, __int_as_float(n));
    } else {
        unsigned int o = atomicAdd(ovfcnt, 1u);
        if (o < (unsigned int)OVFCAP) ovf[o] = n;
    }
}

// ---- Pass 2: per-cell gather (blocks < NCELLS) + overflow tail (the rest).
__global__ __launch_bounds__(512) void cell_gather(
    const unsigned short* __restrict__ vol, const float* __restrict__ xyz,
    const float4* __restrict__ sorted, const unsigned int* __restrict__ cur,
    const unsigned int* __restrict__ ovf, const unsigned int* __restrict__ ovfcnt,
    int CAPS, float* __restrict__ out)
{
    const uint4* vol4 = (const uint4*)vol;
    int bid = blockIdx.x;

    if (bid >= NCELLS) {
        // ---- overflow tail: exact, normally ~0 points ----
        int m = (int)min(*ovfcnt, (unsigned int)OVFCAP);
        for (int i = (bid - NCELLS) * 512 + threadIdx.x; i < m; i += TAILB * 512) {
            int n = (int)ovf[i];
            const float* xp = xyz + (size_t)n * 3;
            float px, py, pz; int ix, iy, iz;
            point_coords(xp[0], xp[1], xp[2], px, py, pz, ix, iy, iz);
            float fx = px - floorf(px), fy = py - floorf(py), fz = pz - floorf(pz);
            float wx[2] = {1.0f - fx, fx}, wy[2] = {1.0f - fy, fy}, wz[2] = {1.0f - fz, fz};
            int ibase = (iz * RR + iy) * RR + ix;
            for (int t = 0; t < 4; ++t) {
                float acc[8];
#pragma unroll
                for (int k = 0; k < 8; ++k) acc[k] = 0.0f;
#pragma unroll
                for (int dz = 0; dz < 2; ++dz)
#pragma unroll
                for (int dy = 0; dy < 2; ++dy)
#pragma unroll
                for (int dx = 0; dx < 2; ++dx) {
                    int vidx = ibase + dz * (RR * RR) + dy * RR + dx;
                    float w = wz[dz] * wy[dy] * wx[dx];
                    corner_accum(vol4[chunk_at(vidx, t)], w, acc);
                }
                float* op = out + (size_t)n * NCH + t * 8;
                if (t < 3) {
                    *(float4*)op       = make_float4(acc[0], acc[1], acc[2], acc[3]);
                    *(float4*)(op + 4) = make_float4(acc[4], acc[5], acc[6], acc[7]);
                } else {
                    *(float4*)op = make_float4(acc[0], acc[1], acc[2], acc[3]);
                }
            }
        }
        return;
    }

    __shared__ uint4 lds16[RV * 4];          // 46,656 B -> 3 blocks/CU
    __shared__ unsigned int pref[NSUB + 1];  // sub-list prefix

    // XCD swizzle: consecutive cells (x-neighbors, shared cache lines) on same XCD.
    int cid = (bid & 7) * (NCELLS / 8) + (bid >> 3);   // 4096 % 8 == 0, bijective
    int cx = cid & 15, cy = (cid >> 4) & 15, cz = cid >> 8;
    int x0 = cx << 3, y0 = cy << 3, z0 = cz << 3;

    if (threadIdx.x == 0) {
        unsigned int a = 0;
        pref[0] = 0;
#pragma unroll
        for (int s = 0; s < NSUB; ++s) {
            a += min(cur[s * NCELLS + cid], (unsigned int)CAPS);
            pref[s + 1] = a;
        }
    }

    // --- region copy: 2916 x 16B. For fixed q, lanes sweep region voxels ->
    //     contiguous 144 B runs per row. LDS slot XOR-swizzled by (v&3). ---
    for (int i = threadIdx.x; i < 4 * RV; i += 512) {
        int q = i / RV;
        int v = i - q * RV;
        int rz = v / 81, rem = v - rz * 81;
        int ry = rem / 9, rx = rem - ry * 9;
        int zg = min(z0 + rz, RR - 1);
        int yg = min(y0 + ry, RR - 1);
        int xg = min(x0 + rx, RR - 1);
        int V = (zg * RR + yg) * RR + xg;
        lds16[v * 4 + (q ^ (v & 3))] = vol4[chunk_at(V, q)];
    }
    __syncthreads();

    // --- point loop over concatenated sub-lists: 4 lanes/point ---
    int total = (int)pref[NSUB];
    int g = threadIdx.x >> 2, t = threadIdx.x & 3;

    for (int vp = g; vp < total; vp += 128) {
        int s = 0;
#pragma unroll
        for (int k = 0; k < NSUB - 1; ++k) s += (vp >= (int)pref[k + 1]);
        int p = vp - (int)pref[s];
        float4 pt = sorted[((size_t)s * NCELLS + cid) * CAPS + p];
        float px = pt.x, py = pt.y, pz = pt.z;
        int idx = __float_as_int(pt.w);

        float fx0 = floorf(px), fy0 = floorf(py), fz0 = floorf(pz);
        float fx = px - fx0, fy = py - fy0, fz = pz - fz0;
        int lx = min(max((int)fx0, 0), RR - 2) - x0;
        int ly = min(max((int)fy0, 0), RR - 2) - y0;
        int lz = min(max((int)fz0, 0), RR - 2) - z0;

        float wx[2] = {1.0f - fx, fx};
        float wy[2] = {1.0f - fy, fy};
        float wz[2] = {1.0f - fz, fz};

        float acc[8];
#pragma unroll
        for (int k = 0; k < 8; ++k) acc[k] = 0.0f;

#pragma unroll
        for (int dz = 0; dz < 2; ++dz)
#pragma unroll
        for (int dy = 0; dy < 2; ++dy)
#pragma unroll
        for (int dx = 0; dx < 2; ++dx) {
            int v = ((lz + dz) * 9 + (ly + dy)) * 9 + (lx + dx);
            float w = wz[dz] * wy[dy] * wx[dx];
            corner_accum(lds16[v * 4 + (t ^ (v & 3))], w, acc);
        }

        float* op = out + (size_t)idx * NCH + t * 8;
        if (t < 3) {
            *(float4*)op       = make_float4(acc[0], acc[1], acc[2], acc[3]);
            *(float4*)(op + 4) = make_float4(acc[4], acc[5], acc[6], acc[7]);
        } else {
            *(float4*)op = make_float4(acc[0], acc[1], acc[2], acc[3]); // ch 24..27
        }
    }
}

// ---- standalone presum (mid fallback path) ----
__global__ __launch_bounds__(256, 4) void presum_kernel(
    const float* __restrict__ bden, const float* __restrict__ bsh,
    const float* __restrict__ dden, const float* __restrict__ dsh,
    unsigned short* __restrict__ vol)
{
    presum_body(blockIdx.x * 256 + threadIdx.x, bden, bsh, dden, dsh, vol);
}

// ---- Mid fallback: direct gather from presummed volume ----
__global__ __launch_bounds__(256) void gather_kernel(
    const float* __restrict__ xyz,
    const unsigned short* __restrict__ vol,
    float* __restrict__ out, int N)
{
    int tid = blockIdx.x * 256 + threadIdx.x;
    int n = tid >> 2;
    int t = tid & 3;
    if (n >= N) return;
    const uint4* vol4 = (const uint4*)vol;

    const float* xp = xyz + (size_t)n * 3;
    float px, py, pz; int ix, iy, iz;
    point_coords(xp[0], xp[1], xp[2], px, py, pz, ix, iy, iz);
    float fx = px - floorf(px), fy = py - floorf(py), fz = pz - floorf(pz);
    float wx[2] = {1.0f - fx, fx}, wy[2] = {1.0f - fy, fy}, wz[2] = {1.0f - fz, fz};

    int ibase = (iz * RR + iy) * RR + ix;

    float acc[8];
#pragma unroll
    for (int k = 0; k < 8; ++k) acc[k] = 0.0f;

#pragma unroll
    for (int dz = 0; dz < 2; ++dz)
#pragma unroll
    for (int dy = 0; dy < 2; ++dy)
#pragma unroll
    for (int dx = 0; dx < 2; ++dx) {
        int vidx = ibase + dz * (RR * RR) + dy * RR + dx;
        float w = wz[dz] * wy[dy] * wx[dx];
        corner_accum(vol4[chunk_at(vidx, t)], w, acc);
    }

    float* op = out + (size_t)n * NCH + t * 8;
    if (t < 3) {
        *(float4*)op       = make_float4(acc[0], acc[1], acc[2], acc[3]);
        *(float4*)(op + 4) = make_float4(acc[4], acc[5], acc[6], acc[7]);
    } else {
        *(float4*)op = make_float4(acc[0], acc[1], acc[2], acc[3]);
    }
}

// ---- Last-resort fallback: direct dual-grid gather ----
__global__ __launch_bounds__(256) void gather_fallback(
    const float* __restrict__ xyz,
    const float* __restrict__ bden, const float* __restrict__ bsh,
    const float* __restrict__ dden, const float* __restrict__ dsh,
    float* __restrict__ out, int N)
{
    int n = blockIdx.x * 256 + threadIdx.x;
    if (n >= N) return;
    const float* xp = xyz + (size_t)n * 3;
    float px, py, pz; int ix, iy, iz;
    point_coords(xp[0], xp[1], xp[2], px, py, pz, ix, iy, iz);
    float fx = px - floorf(px), fy = py - floorf(py), fz = pz - floorf(pz);
    float wx[2] = {1.0f - fx, fx}, wy[2] = {1.0f - fy, fy}, wz[2] = {1.0f - fz, fz};

    int idx[8]; float w[8];
#pragma unroll
    for (int k = 0; k < 8; ++k) {
        int dz = (k >> 2) & 1, dy = (k >> 1) & 1, dx = k & 1;
        idx[k] = ((iz + dz) * RR + (iy + dy)) * RR + (ix + dx);
        w[k] = wz[dz] * wy[dy] * wx[dx];
    }
#pragma unroll
    for (int c = 0; c < NCH; ++c) {
        const float* bp = (c == 0) ? bden : (bsh + (size_t)(c - 1) * VV);
        const float* dp = (c == 0) ? dden : (dsh + (size_t)(c - 1) * VV);
        float a = 0.0f;
#pragma unroll
        for (int k = 0; k < 8; ++k)
            a = fmaf(w[k], bp[idx[k]] + dp[idx[k]], a);
        out[(size_t)n * NCH + c] = a;
    }
}

extern "C" void kernel_launch(void* const* d_in, const int* in_sizes, int n_in,
                              void* d_out, int out_size, void* d_ws, size_t ws_size,
                              hipStream_t stream) {
    const float* xyz  = (const float*)d_in[0];
    const float* bden = (const float*)d_in[1];
    const float* bsh  = (const float*)d_in[2];
    const float* dden = (const float*)d_in[3];
    const float* dsh  = (const float*)d_in[4];
    float* out = (float*)d_out;
    int N = in_sizes[0] / 3;
    if (N <= 0) return;

    size_t volBytes = (size_t)VV * CPAD * sizeof(unsigned short);   // 134,217,728
    size_t ovfBytes = (size_t)OVFCAP * 4;                           // 4 MB
    size_t ctrBytes = (size_t)(NSUB * NCELLS + 1) * 4;              // cur + ovfcnt

    // Adaptive per-sub-bucket capacity: target mean + 5*sigma.
    int nb = NSUB * NCELLS;
    int mean = (N + nb - 1) / nb;
    double sg = sqrt((double)mean);
    int target  = mean + (int)(5.0 * sg) + 8;
    int capsMin = mean + (int)(1.5 * sg) + 2;

    long long avail = (long long)ws_size - (long long)(volBytes + ovfBytes + ctrBytes + 64);
    int CAPS = 0;
    if (avail > 0) {
        long long c = avail / ((long long)nb * 16);
        CAPS = (int)(c > target ? target : c);
    }

    if (CAPS >= capsMin) {
        // layout: sorted | vol | ovf | cur | ovfcnt
        char* w = (char*)d_ws;
        float4* sorted      = (float4*)w;
        size_t sortedBytes  = (size_t)nb * CAPS * 16;
        unsigned short* vol = (unsigned short*)(w + sortedBytes);
        unsigned int* ovf   = (unsigned int*)(w + sortedBytes + volBytes);
        unsigned int* cur   = (unsigned int*)(w + sortedBytes + volBytes + ovfBytes);
        unsigned int* ovfcnt = cur + NSUB * NCELLS;

        hipMemsetAsync(cur, 0, ctrBytes, stream);
        int presumBlocks  = VV / 256;
        int scatterBlocks = (N + 255) / 256;
        presum_scatter<<<presumBlocks + scatterBlocks, 256, 0, stream>>>(
            bden, bsh, dden, dsh, xyz, N, CAPS,
            vol, sorted, cur, ovf, ovfcnt, presumBlocks);
        cell_gather<<<NCELLS + TAILB, 512, 0, stream>>>(
            vol, xyz, sorted, cur, ovf, ovfcnt, CAPS, out);
    } else if (ws_size >= volBytes) {
        presum_kernel<<<VV / 256, 256, 0, stream>>>(
            bden, bsh, dden, dsh, (unsigned short*)d_ws);
        long long threads = (long long)N * 4;
        gather_kernel<<<(unsigned int)((threads + 255) / 256), 256, 0, stream>>>(
            xyz, (const unsigned short*)d_ws, out, N);
    } else {
        gather_fallback<<<(N + 255) / 256, 256, 0, stream>>>(
            xyz, bden, bsh, dden, dsh, out, N);
    }
}